// Round 1
// baseline (1243.724 us; speedup 1.0000x reference)
//
#include <hip/hip_runtime.h>

#define DIN 256
#define H   128
#define DOUT 64

#define EPI_RELU 0
#define EPI_BN   1
#define EPI_NONE 2

// ---------------- CSR build ----------------
__global__ __launch_bounds__(256) void hist_kernel(const int* __restrict__ dst,
                                                   int* __restrict__ deg, int e) {
  int i = blockIdx.x * blockDim.x + threadIdx.x;
  if (i < e) atomicAdd(&deg[dst[i]], 1);
}

__global__ __launch_bounds__(1024) void scan_kernel(const int* __restrict__ deg,
                                                    int* __restrict__ row_ptr,
                                                    int* __restrict__ cursor, int n) {
  __shared__ int sm[1024];
  int tid = threadIdx.x;
  int base = 0;
  for (int start = 0; start < n; start += 1024) {
    int i = start + tid;
    int v = (i < n) ? deg[i] : 0;
    sm[tid] = v;
    __syncthreads();
    for (int off = 1; off < 1024; off <<= 1) {
      int t = (tid >= off) ? sm[tid - off] : 0;
      __syncthreads();
      sm[tid] += t;
      __syncthreads();
    }
    int incl = sm[tid];
    if (i < n) {
      int rp = base + incl - v;
      row_ptr[i] = rp;
      cursor[i] = rp;
    }
    base += sm[1023];
    __syncthreads();  // protect sm before next chunk overwrites
  }
  if (tid == 0) row_ptr[n] = base;
}

__global__ __launch_bounds__(256) void fill_kernel(const int* __restrict__ src,
                                                   const int* __restrict__ dst,
                                                   int* __restrict__ cursor,
                                                   int* __restrict__ csr_src, int e) {
  int i = blockIdx.x * blockDim.x + threadIdx.x;
  if (i < e) {
    int p = atomicAdd(&cursor[dst[i]], 1);
    csr_src[p] = src[i];
  }
}

// ---------------- mean aggregation: one wave per node ----------------
__global__ __launch_bounds__(256) void agg_kernel(const float* __restrict__ h,
                                                  const int* __restrict__ row_ptr,
                                                  const int* __restrict__ csr_src,
                                                  float* __restrict__ mean, int n) {
  int node = (int)((blockIdx.x * blockDim.x + threadIdx.x) >> 6);
  int lane = threadIdx.x & 63;
  if (node >= n) return;
  int beg = row_ptr[node], end = row_ptr[node + 1];
  float2 acc = make_float2(0.f, 0.f);
  const float2* hp = (const float2*)h;
  for (int j = beg; j < end; ++j) {
    int s = csr_src[j];
    float2 v = hp[(size_t)s * (H / 2) + lane];
    acc.x += v.x;
    acc.y += v.y;
  }
  int d = end - beg;
  float invd = 1.0f / (float)(d > 0 ? d : 1);
  ((float2*)mean)[(size_t)node * (H / 2) + lane] =
      make_float2(acc.x * invd, acc.y * invd);
}

// ---------------- fp32 tiled GEMM: C = epi(A1@W1 [+ A2@W2] + bias) ----------------
// A: [n, K] row-major, W: [K, M] row-major. BM=64 rows/block, 256 threads,
// thread (ty=tid/32, tx=tid%32) computes rows ty*8..+7, cols tx+32*j.
template <int K1, int K2, int M, int EPI>
__global__ __launch_bounds__(256) void gemm_kernel(
    const float* __restrict__ A1, const float* __restrict__ A2,
    const float* __restrict__ W1, const float* __restrict__ W2,
    const float* __restrict__ bias, const float* __restrict__ gamma,
    const float* __restrict__ beta, float* __restrict__ C, int n) {
  constexpr int BM = 64, BK = 32;
  constexpr int NC = M / 32;
  __shared__ float As[BM][BK + 1];
  __shared__ float Bs[BK][M];

  int tid = threadIdx.x;
  int tx = tid & 31;
  int ty = tid >> 5;
  int row0 = blockIdx.x * BM;

  float acc[8][NC];
#pragma unroll
  for (int i = 0; i < 8; ++i)
#pragma unroll
    for (int j = 0; j < NC; ++j) acc[i][j] = 0.f;

  auto do_mat = [&](const float* __restrict__ A, const float* __restrict__ W, int K) {
    for (int kt = 0; kt < K; kt += BK) {
      // --- A tile: 64 rows x 32 k.  4 threads/row, 8 floats each (2x float4)
      {
        int r = tid >> 2;
        int c8 = (tid & 3) * 8;
        int row = row0 + r;
        if (row >= n) row = n - 1;
        const float4* ap = (const float4*)(A + (size_t)row * K + kt + c8);
        float4 v0 = ap[0];
        float4 v1 = ap[1];
        As[r][c8 + 0] = v0.x; As[r][c8 + 1] = v0.y;
        As[r][c8 + 2] = v0.z; As[r][c8 + 3] = v0.w;
        As[r][c8 + 4] = v1.x; As[r][c8 + 5] = v1.y;
        As[r][c8 + 6] = v1.z; As[r][c8 + 7] = v1.w;
      }
      // --- B tile: 32 k x M
      {
        constexpr int TPR = M / 4;        // threads per row
        constexpr int RPP = 256 / TPR;    // rows per pass
#pragma unroll
        for (int p = 0; p < BK / RPP; ++p) {
          int k = p * RPP + tid / TPR;
          int c4 = (tid % TPR) * 4;
          float4 v = *(const float4*)(W + (size_t)(kt + k) * M + c4);
          *(float4*)&Bs[k][c4] = v;
        }
      }
      __syncthreads();
#pragma unroll
      for (int k = 0; k < BK; ++k) {
        float a[8];
#pragma unroll
        for (int i = 0; i < 8; ++i) a[i] = As[ty * 8 + i][k];
#pragma unroll
        for (int j = 0; j < NC; ++j) {
          float b = Bs[k][tx + 32 * j];
#pragma unroll
          for (int i = 0; i < 8; ++i) acc[i][j] += a[i] * b;
        }
      }
      __syncthreads();
    }
  };

  do_mat(A1, W1, K1);
  if constexpr (K2 > 0) do_mat(A2, W2, K2);

  // epilogue
  const float inv_std = 1.0f / sqrtf(1.0f + 1e-5f);  // constant-folds
#pragma unroll
  for (int j = 0; j < NC; ++j) {
    int col = tx + 32 * j;
    float b = bias[col];
    float sc = 0.f, bt = 0.f;
    if (EPI == EPI_BN) {
      sc = gamma[col] * inv_std;
      bt = beta[col];
    }
#pragma unroll
    for (int i = 0; i < 8; ++i) {
      int row = row0 + ty * 8 + i;
      if (row < n) {
        float v = acc[i][j] + b;
        if (EPI == EPI_BN) {
          v = v * sc + bt;
          v = fmaxf(v, 0.f);
        } else if (EPI == EPI_RELU) {
          v = fmaxf(v, 0.f);
        }
        C[(size_t)row * M + col] = v;
      }
    }
  }
}

extern "C" void kernel_launch(void* const* d_in, const int* in_sizes, int n_in,
                              void* d_out, int out_size, void* d_ws, size_t ws_size,
                              hipStream_t stream) {
  const float* x     = (const float*)d_in[0];
  const int*   ei    = (const int*)d_in[1];
  const float* w_in  = (const float*)d_in[2];
  const float* b_in  = (const float*)d_in[3];
  const float* w_l1  = (const float*)d_in[4];
  const float* b_l1  = (const float*)d_in[5];
  const float* w_r1  = (const float*)d_in[6];
  const float* g1    = (const float*)d_in[7];
  const float* be1   = (const float*)d_in[8];
  const float* w_l2  = (const float*)d_in[9];
  const float* b_l2  = (const float*)d_in[10];
  const float* w_r2  = (const float*)d_in[11];
  const float* g2    = (const float*)d_in[12];
  const float* be2   = (const float*)d_in[13];
  const float* w_out = (const float*)d_in[14];
  const float* b_out = (const float*)d_in[15];
  float* out = (float*)d_out;

  int N = in_sizes[0] / DIN;
  int E = in_sizes[1] / 2;
  const int* src = ei;       // edge_index[0]
  const int* dst = ei + E;   // edge_index[1]

  char* ws = (char*)d_ws;
  size_t off = 0;
  auto alloc = [&](size_t bytes) -> char* {
    char* p = ws + off;
    off += (bytes + 255) & ~(size_t)255;
    return p;
  };
  float* buf0 = (float*)alloc((size_t)N * H * 4);  // h0, later mean2
  float* buf1 = (float*)alloc((size_t)N * H * 4);  // mean1, later h2
  float* buf2 = (float*)alloc((size_t)N * H * 4);  // h1
  int* deg     = (int*)alloc((size_t)N * 4);
  int* row_ptr = (int*)alloc((size_t)(N + 1) * 4);
  int* cursor  = (int*)alloc((size_t)N * 4);
  int* csr_src = (int*)alloc((size_t)E * 4);
  (void)ws_size;

  // ---- CSR build (shared by both SAGE layers) ----
  hipMemsetAsync(deg, 0, (size_t)N * 4, stream);
  hist_kernel<<<(E + 255) / 256, 256, 0, stream>>>(dst, deg, E);
  scan_kernel<<<1, 1024, 0, stream>>>(deg, row_ptr, cursor, N);
  fill_kernel<<<(E + 255) / 256, 256, 0, stream>>>(src, dst, cursor, csr_src, E);

  int gblocks = (N + 63) / 64;
  int ablocks = (N + 3) / 4;  // 4 waves (nodes) per 256-thread block

  // h0 = relu(x @ w_in + b_in)
  gemm_kernel<DIN, 0, H, EPI_RELU><<<gblocks, 256, 0, stream>>>(
      x, nullptr, w_in, nullptr, b_in, nullptr, nullptr, buf0, N);
  // mean1
  agg_kernel<<<ablocks, 256, 0, stream>>>(buf0, row_ptr, csr_src, buf1, N);
  // h1 = relu(bn(mean1@w_l1 + h0@w_r1 + b_l1))
  gemm_kernel<H, H, H, EPI_BN><<<gblocks, 256, 0, stream>>>(
      buf1, buf0, w_l1, w_r1, b_l1, g1, be1, buf2, N);
  // mean2
  agg_kernel<<<ablocks, 256, 0, stream>>>(buf2, row_ptr, csr_src, buf0, N);
  // h2 = relu(bn(mean2@w_l2 + h1@w_r2 + b_l2))
  gemm_kernel<H, H, H, EPI_BN><<<gblocks, 256, 0, stream>>>(
      buf0, buf2, w_l2, w_r2, b_l2, g2, be2, buf1, N);
  // out = h2 @ w_out + b_out
  gemm_kernel<H, 0, DOUT, EPI_NONE><<<gblocks, 256, 0, stream>>>(
      buf1, nullptr, w_out, nullptr, b_out, nullptr, nullptr, out, N);
}

// Round 2
// 791.179 us; speedup vs baseline: 1.5720x; 1.5720x over previous
//
#include <hip/hip_runtime.h>

#define DIN 256
#define H   128
#define DOUT 64

#define EPI_RELU 0
#define EPI_BN   1
#define EPI_NONE 2

typedef __attribute__((ext_vector_type(8))) short bf16x8;
typedef __attribute__((ext_vector_type(4))) float f32x4;

__device__ inline unsigned short f2bf(float f) {
  union { float f; unsigned u; } v; v.f = f;
  unsigned u = v.u;
  u += 0x7FFFu + ((u >> 16) & 1u);   // round-to-nearest-even
  return (unsigned short)(u >> 16);
}
__device__ inline float bf2f(unsigned short b) {
  union { unsigned u; float f; } v; v.u = ((unsigned)b) << 16;
  return v.f;
}

// ---------------- CSR build (scan-free) ----------------
__global__ __launch_bounds__(256) void hist_kernel(const int* __restrict__ dst,
                                                   int* __restrict__ deg, int e) {
  int i = blockIdx.x * blockDim.x + threadIdx.x;
  if (i < e) atomicAdd(&deg[dst[i]], 1);
}

// Reserve a contiguous slot range per node via one atomic each.
// Ordering of ranges is arbitrary — agg only needs [beg, beg+deg).
__global__ __launch_bounds__(256) void alloc_kernel(const int* __restrict__ deg,
                                                    int* __restrict__ counter,
                                                    int* __restrict__ row_beg,
                                                    int* __restrict__ cursor, int n) {
  int i = blockIdx.x * blockDim.x + threadIdx.x;
  if (i < n) {
    int d = deg[i];
    int p = atomicAdd(counter, d);
    row_beg[i] = p;
    cursor[i] = p;
  }
}

__global__ __launch_bounds__(256) void fill_kernel(const int* __restrict__ src,
                                                   const int* __restrict__ dst,
                                                   int* __restrict__ cursor,
                                                   int* __restrict__ csr_src, int e) {
  int i = blockIdx.x * blockDim.x + threadIdx.x;
  if (i < e) {
    int p = atomicAdd(&cursor[dst[i]], 1);
    csr_src[p] = src[i];
  }
}

// ---------------- mean aggregation: one wave per node, bf16 features ----------------
__global__ __launch_bounds__(256) void agg_kernel(const unsigned* __restrict__ h,
                                                  const int* __restrict__ row_beg,
                                                  const int* __restrict__ deg,
                                                  const int* __restrict__ csr_src,
                                                  unsigned* __restrict__ mean, int n) {
  int node = (int)((blockIdx.x * blockDim.x + threadIdx.x) >> 6);
  if (node >= n) return;
  int lane = threadIdx.x & 63;
  int beg = row_beg[node], d = deg[node];
  float ax = 0.f, ay = 0.f;
  for (int j = 0; j < d; ++j) {
    int s = csr_src[beg + j];
    unsigned v = h[(size_t)s * (H / 2) + lane];
    ax += bf2f((unsigned short)(v & 0xffffu));
    ay += bf2f((unsigned short)(v >> 16));
  }
  float invd = 1.f / (float)(d > 0 ? d : 1);
  unsigned lo = f2bf(ax * invd);
  unsigned hi = f2bf(ay * invd);
  mean[(size_t)node * (H / 2) + lane] = lo | (hi << 16);
}

// ---------------- bf16 MFMA GEMM ----------------
// Block: 256 threads = 4 waves; tile 64 rows x M cols; BK=32 (one MFMA K).
// A staged row-major [64][32] bf16 (padded stride 40), W staged TRANSPOSED
// [M][32] bf16 (padded 40) so B k-strips are contiguous for ds_read_b128.
// MFMA 16x16x32_bf16 layouts: A[m=lane&15][k=quad*8+j]; B[k=quad*8+j][n=lane&15];
// D col=lane&15, row=quad*4+reg.
template <bool AFP32, int K, int M>
__device__ inline void run_mat(const void* __restrict__ Av, const float* __restrict__ W,
                               unsigned short* As, unsigned short* Bt,
                               f32x4* acc, int n, int row0) {
  constexpr int LDT = 40;
  constexpr int NT = M / 16;
  constexpr int TPC = 256 / M;       // threads per W column
  constexpr int KCH = 32 / TPC;      // k elems staged per thread
  int tid = threadIdx.x;
  int lane = tid & 63, wave = tid >> 6;
  int m16 = lane & 15, quad = lane >> 4;
  int bcol = tid % M;
  int bk0 = (tid / M) * KCH;
  int ar = tid >> 2;
  int ac8 = (tid & 3) * 8;
  int arow = row0 + ar;
  if (arow >= n) arow = n - 1;

  for (int kt = 0; kt < K; kt += 32) {
    // --- stage A tile (64 x 32 bf16)
    {
      uint4 pk;
      if constexpr (AFP32) {
        const float* ap = (const float*)Av + (size_t)arow * K + kt + ac8;
        float4 v0 = *(const float4*)ap;
        float4 v1 = *(const float4*)(ap + 4);
        pk.x = f2bf(v0.x) | ((unsigned)f2bf(v0.y) << 16);
        pk.y = f2bf(v0.z) | ((unsigned)f2bf(v0.w) << 16);
        pk.z = f2bf(v1.x) | ((unsigned)f2bf(v1.y) << 16);
        pk.w = f2bf(v1.z) | ((unsigned)f2bf(v1.w) << 16);
      } else {
        const unsigned short* ap = (const unsigned short*)Av + (size_t)arow * K + kt + ac8;
        pk = *(const uint4*)ap;
      }
      *(uint4*)&As[ar * LDT + ac8] = pk;
    }
    // --- stage B tile transposed: Bt[col][k] = W[kt+k][col], fp32 -> bf16
    {
      unsigned pk[KCH / 2];
#pragma unroll
      for (int j = 0; j < KCH; j += 2) {
        float w0 = W[(size_t)(kt + bk0 + j) * M + bcol];
        float w1 = W[(size_t)(kt + bk0 + j + 1) * M + bcol];
        pk[j / 2] = f2bf(w0) | ((unsigned)f2bf(w1) << 16);
      }
#pragma unroll
      for (int q = 0; q < KCH / 8; ++q)
        *(uint4*)&Bt[bcol * LDT + bk0 + q * 8] =
            make_uint4(pk[q * 4], pk[q * 4 + 1], pk[q * 4 + 2], pk[q * 4 + 3]);
    }
    __syncthreads();
    bf16x8 af = *(const bf16x8*)&As[(wave * 16 + m16) * LDT + quad * 8];
#pragma unroll
    for (int t = 0; t < NT; ++t) {
      bf16x8 bfr = *(const bf16x8*)&Bt[(t * 16 + m16) * LDT + quad * 8];
      acc[t] = __builtin_amdgcn_mfma_f32_16x16x32_bf16(af, bfr, acc[t], 0, 0, 0);
    }
    __syncthreads();
  }
}

template <int K1, int K2, int M, int EPI, bool AFP32, bool OUTF32>
__global__ __launch_bounds__(256) void gemm_mfma(
    const void* __restrict__ A1, const void* __restrict__ A2,
    const float* __restrict__ W1, const float* __restrict__ W2,
    const float* __restrict__ bias, const float* __restrict__ gamma,
    const float* __restrict__ beta, void* __restrict__ Cv, int n) {
  constexpr int LDT = 40;
  constexpr int NT = M / 16;
  __shared__ __align__(16) unsigned short As[64 * LDT];
  __shared__ __align__(16) unsigned short Bt[M * LDT];
  f32x4 acc[NT];
#pragma unroll
  for (int t = 0; t < NT; ++t) acc[t] = (f32x4){0.f, 0.f, 0.f, 0.f};
  int row0 = blockIdx.x * 64;
  run_mat<AFP32, K1, M>(A1, W1, As, Bt, acc, n, row0);
  if constexpr (K2 > 0) run_mat<false, K2, M>(A2, W2, As, Bt, acc, n, row0);

  int lane = threadIdx.x & 63, wave = threadIdx.x >> 6;
  int m16 = lane & 15, quad = lane >> 4;
  const float inv_std = rsqrtf(1.f + 1e-5f);
#pragma unroll
  for (int t = 0; t < NT; ++t) {
    int col = t * 16 + m16;
    float bv = bias[col];
    float sc = 1.f, bt2 = 0.f;
    if constexpr (EPI == EPI_BN) {
      sc = gamma[col] * inv_std;
      bt2 = beta[col];
    }
#pragma unroll
    for (int r = 0; r < 4; ++r) {
      int row = row0 + wave * 16 + quad * 4 + r;
      if (row < n) {
        float v = acc[t][r] + bv;
        if constexpr (EPI == EPI_BN) v = fmaxf(v * sc + bt2, 0.f);
        else if constexpr (EPI == EPI_RELU) v = fmaxf(v, 0.f);
        if constexpr (OUTF32)
          ((float*)Cv)[(size_t)row * M + col] = v;
        else
          ((unsigned short*)Cv)[(size_t)row * M + col] = f2bf(v);
      }
    }
  }
}

extern "C" void kernel_launch(void* const* d_in, const int* in_sizes, int n_in,
                              void* d_out, int out_size, void* d_ws, size_t ws_size,
                              hipStream_t stream) {
  const float* x     = (const float*)d_in[0];
  const int*   ei    = (const int*)d_in[1];
  const float* w_in  = (const float*)d_in[2];
  const float* b_in  = (const float*)d_in[3];
  const float* w_l1  = (const float*)d_in[4];
  const float* b_l1  = (const float*)d_in[5];
  const float* w_r1  = (const float*)d_in[6];
  const float* g1    = (const float*)d_in[7];
  const float* be1   = (const float*)d_in[8];
  const float* w_l2  = (const float*)d_in[9];
  const float* b_l2  = (const float*)d_in[10];
  const float* w_r2  = (const float*)d_in[11];
  const float* g2    = (const float*)d_in[12];
  const float* be2   = (const float*)d_in[13];
  const float* w_out = (const float*)d_in[14];
  const float* b_out = (const float*)d_in[15];
  float* out = (float*)d_out;

  int N = in_sizes[0] / DIN;
  int E = in_sizes[1] / 2;
  const int* src = ei;       // edge_index[0]
  const int* dst = ei + E;   // edge_index[1]

  char* ws = (char*)d_ws;
  size_t off = 0;
  auto alloc = [&](size_t bytes) -> char* {
    char* p = ws + off;
    off += (bytes + 255) & ~(size_t)255;
    return p;
  };
  unsigned short* buf0 = (unsigned short*)alloc((size_t)N * H * 2);  // h0 -> mean2
  unsigned short* buf1 = (unsigned short*)alloc((size_t)N * H * 2);  // mean1 -> h2
  unsigned short* buf2 = (unsigned short*)alloc((size_t)N * H * 2);  // h1
  int* deg     = (int*)alloc((size_t)(N + 1) * 4);  // deg[N] is the alloc counter
  int* row_beg = (int*)alloc((size_t)N * 4);
  int* cursor  = (int*)alloc((size_t)N * 4);
  int* csr_src = (int*)alloc((size_t)E * 4);
  int* counter = deg + N;
  (void)ws_size;

  // ---- CSR build (shared by both SAGE layers) ----
  hipMemsetAsync(deg, 0, (size_t)(N + 1) * 4, stream);
  hist_kernel<<<(E + 255) / 256, 256, 0, stream>>>(dst, deg, E);
  alloc_kernel<<<(N + 255) / 256, 256, 0, stream>>>(deg, counter, row_beg, cursor, N);
  fill_kernel<<<(E + 255) / 256, 256, 0, stream>>>(src, dst, cursor, csr_src, E);

  int gblocks = (N + 63) / 64;
  int ablocks = (N + 3) / 4;  // 4 nodes (waves) per 256-thread block

  // h0 = relu(x @ w_in + b_in)                             [fp32 in, bf16 out]
  gemm_mfma<DIN, 0, H, EPI_RELU, true, false><<<gblocks, 256, 0, stream>>>(
      x, nullptr, w_in, nullptr, b_in, nullptr, nullptr, buf0, N);
  // mean1 = mean-agg(h0)
  agg_kernel<<<ablocks, 256, 0, stream>>>((const unsigned*)buf0, row_beg, deg,
                                          csr_src, (unsigned*)buf1, N);
  // h1 = relu(bn(mean1@w_l1 + h0@w_r1 + b_l1))
  gemm_mfma<H, H, H, EPI_BN, false, false><<<gblocks, 256, 0, stream>>>(
      buf1, buf0, w_l1, w_r1, b_l1, g1, be1, buf2, N);
  // mean2 = mean-agg(h1)
  agg_kernel<<<ablocks, 256, 0, stream>>>((const unsigned*)buf2, row_beg, deg,
                                          csr_src, (unsigned*)buf0, N);
  // h2 = relu(bn(mean2@w_l2 + h1@w_r2 + b_l2))
  gemm_mfma<H, H, H, EPI_BN, false, false><<<gblocks, 256, 0, stream>>>(
      buf0, buf2, w_l2, w_r2, b_l2, g2, be2, buf1, N);
  // out = h2 @ w_out + b_out                               [bf16 in, fp32 out]
  gemm_mfma<H, 0, DOUT, EPI_NONE, false, true><<<gblocks, 256, 0, stream>>>(
      buf1, nullptr, w_out, nullptr, b_out, nullptr, nullptr, out, N);
}

// Round 3
// 645.109 us; speedup vs baseline: 1.9279x; 1.2264x over previous
//
#include <hip/hip_runtime.h>

#define DIN 256
#define H   128
#define DOUT 64

#define EPI_RELU 0
#define EPI_BN   1
#define EPI_NONE 2

typedef __attribute__((ext_vector_type(8))) short bf16x8;
typedef __attribute__((ext_vector_type(4))) float f32x4;

__device__ inline unsigned short f2bf(float f) {
  union { float f; unsigned u; } v; v.f = f;
  unsigned u = v.u;
  u += 0x7FFFu + ((u >> 16) & 1u);   // round-to-nearest-even
  return (unsigned short)(u >> 16);
}
__device__ inline float bf2f(unsigned u16) {
  union { unsigned u; float f; } v; v.u = u16 << 16;
  return v.f;
}

// ---------------- CSR build (scan-free) ----------------
__global__ __launch_bounds__(256) void hist_kernel(const int* __restrict__ dst,
                                                   int* __restrict__ deg, int e) {
  int i = blockIdx.x * blockDim.x + threadIdx.x;
  if (i < e) atomicAdd(&deg[dst[i]], 1);
}

__global__ __launch_bounds__(256) void alloc_kernel(const int* __restrict__ deg,
                                                    int* __restrict__ counter,
                                                    int* __restrict__ row_beg,
                                                    int* __restrict__ cursor, int n) {
  int i = blockIdx.x * blockDim.x + threadIdx.x;
  if (i < n) {
    int d = deg[i];
    int p = atomicAdd(counter, d);
    row_beg[i] = p;
    cursor[i] = p;
  }
}

__global__ __launch_bounds__(256) void fill_kernel(const int* __restrict__ src,
                                                   const int* __restrict__ dst,
                                                   int* __restrict__ cursor,
                                                   int* __restrict__ csr_src, int e) {
  int i = blockIdx.x * blockDim.x + threadIdx.x;
  if (i < e) {
    int p = atomicAdd(&cursor[dst[i]], 1);
    csr_src[p] = src[i];
  }
}

// ---------------- weight preconvert: Wt[m][k] = bf16(W[k][m]) ----------------
__global__ __launch_bounds__(256) void prep_w(
    const float* __restrict__ w_in, const float* __restrict__ w_l1,
    const float* __restrict__ w_r1, const float* __restrict__ w_l2,
    const float* __restrict__ w_r2, const float* __restrict__ w_out,
    unsigned short* __restrict__ t_in, unsigned short* __restrict__ t_l1,
    unsigned short* __restrict__ t_r1, unsigned short* __restrict__ t_l2,
    unsigned short* __restrict__ t_r2, unsigned short* __restrict__ t_out) {
  int i = blockIdx.x * 256 + threadIdx.x;
  const float* s; unsigned short* d; int K, M, off;
  if (i < 32768)       { s = w_in;  d = t_in;  K = 256; M = 128; off = i; }
  else if (i < 49152)  { s = w_l1;  d = t_l1;  K = 128; M = 128; off = i - 32768; }
  else if (i < 65536)  { s = w_r1;  d = t_r1;  K = 128; M = 128; off = i - 49152; }
  else if (i < 81920)  { s = w_l2;  d = t_l2;  K = 128; M = 128; off = i - 65536; }
  else if (i < 98304)  { s = w_r2;  d = t_r2;  K = 128; M = 128; off = i - 81920; }
  else if (i < 106496) { s = w_out; d = t_out; K = 128; M = 64;  off = i - 98304; }
  else return;
  int m = off / K, k = off % K;
  d[off] = f2bf(s[(size_t)k * M + m]);
}

// ---------------- mean aggregation: one wave per node, unrolled gather ----------------
__global__ __launch_bounds__(256) void agg_kernel(const unsigned* __restrict__ h,
                                                  const int* __restrict__ row_beg,
                                                  const int* __restrict__ deg,
                                                  const int* __restrict__ csr_src,
                                                  unsigned* __restrict__ mean, int n) {
  int node = (int)((blockIdx.x * blockDim.x + threadIdx.x) >> 6);
  if (node >= n) return;
  int lane = threadIdx.x & 63;
  int beg = row_beg[node], d = deg[node];
  float ax = 0.f, ay = 0.f;
  for (int j0 = 0; j0 < d; j0 += 64) {
    int cnt = min(64, d - j0);
    int li = j0 + (lane < cnt ? lane : cnt - 1);
    int sv = csr_src[beg + li];     // lane j holds csr_src for edge j0+j
    int j = 0;
    for (; j + 4 <= cnt; j += 4) {
      int s0 = __shfl(sv, j);
      int s1 = __shfl(sv, j + 1);
      int s2 = __shfl(sv, j + 2);
      int s3 = __shfl(sv, j + 3);
      unsigned v0 = h[(size_t)s0 * (H / 2) + lane];
      unsigned v1 = h[(size_t)s1 * (H / 2) + lane];
      unsigned v2 = h[(size_t)s2 * (H / 2) + lane];
      unsigned v3 = h[(size_t)s3 * (H / 2) + lane];
      ax += bf2f(v0 & 0xffffu) + bf2f(v1 & 0xffffu) +
            bf2f(v2 & 0xffffu) + bf2f(v3 & 0xffffu);
      ay += bf2f(v0 >> 16) + bf2f(v1 >> 16) + bf2f(v2 >> 16) + bf2f(v3 >> 16);
    }
    for (; j < cnt; ++j) {
      int s = __shfl(sv, j);
      unsigned v = h[(size_t)s * (H / 2) + lane];
      ax += bf2f(v & 0xffffu);
      ay += bf2f(v >> 16);
    }
  }
  float invd = 1.f / (float)(d > 0 ? d : 1);
  mean[(size_t)node * (H / 2) + lane] =
      (unsigned)f2bf(ax * invd) | ((unsigned)f2bf(ay * invd) << 16);
}

// ---------------- bf16 MFMA GEMM, barrier-free k-loop ----------------
// Block: 256 threads = 4 waves, 128 rows (wave w: rows w*32..w*32+31, 2x16 tiles).
// Per phase: stage full Wt[M][128] bf16 into LDS [M][136] (pad 8 -> 2-way free),
// then k-loop: A-frags DIRECT from global (row-major bf16/fp32 rows match the
// 16x16x32 A layout: lane(m16,quad) holds A[row0+rt*16+m16][kt+quad*8+j]),
// B-frags via ds_read_b128. No __syncthreads inside the k-loop.
template <int NPH, int KOFF2, int AK, int M, int EPI, bool AFP32, bool OUTF32>
__global__ __launch_bounds__(256) void gemm_mfma(
    const void* __restrict__ A1, const void* __restrict__ A2,
    const unsigned short* __restrict__ W1, const unsigned short* __restrict__ W2,
    const float* __restrict__ bias, const float* __restrict__ gamma,
    const float* __restrict__ beta, void* __restrict__ Cv, int n) {
  constexpr int KP = 136;            // 128 + 8 pad
  constexpr int NT = M / 16;
  __shared__ __align__(16) unsigned short Bs[M * KP];

  int tid = threadIdx.x, lane = tid & 63, wave = tid >> 6;
  int m16 = lane & 15, quad = lane >> 4;
  int row0 = blockIdx.x * 128;

  f32x4 acc[2][NT];
#pragma unroll
  for (int rt = 0; rt < 2; ++rt)
#pragma unroll
    for (int t = 0; t < NT; ++t) acc[rt][t] = (f32x4){0.f, 0.f, 0.f, 0.f};

  int rowa[2];
#pragma unroll
  for (int rt = 0; rt < 2; ++rt) {
    int r = row0 + wave * 32 + rt * 16 + m16;
    rowa[rt] = (r < n) ? r : (n - 1);
  }

#pragma unroll
  for (int ph = 0; ph < NPH; ++ph) {
    const void* A = ph ? A2 : A1;
    const unsigned short* W = ph ? W2 : W1;
    const int koff = ph ? KOFF2 : 0;
    if (ph) __syncthreads();  // all waves done reading Bs of prior phase
    // stage Wt[M][koff..koff+127] -> Bs[M][136]
    for (int i = tid; i < M * 16; i += 256) {
      int r = i >> 4, c = i & 15;
      *(uint4*)&Bs[r * KP + c * 8] = *(const uint4*)&W[(size_t)r * AK + koff + c * 8];
    }
    __syncthreads();
#pragma unroll
    for (int kt = 0; kt < 128; kt += 32) {
      bf16x8 af[2];
#pragma unroll
      for (int rt = 0; rt < 2; ++rt) {
        if constexpr (AFP32) {
          const float* ap = (const float*)A + (size_t)rowa[rt] * AK + koff + kt + quad * 8;
          float4 v0 = *(const float4*)ap;
          float4 v1 = *(const float4*)(ap + 4);
          union { bf16x8 v; unsigned u[4]; } p;
          p.u[0] = (unsigned)f2bf(v0.x) | ((unsigned)f2bf(v0.y) << 16);
          p.u[1] = (unsigned)f2bf(v0.z) | ((unsigned)f2bf(v0.w) << 16);
          p.u[2] = (unsigned)f2bf(v1.x) | ((unsigned)f2bf(v1.y) << 16);
          p.u[3] = (unsigned)f2bf(v1.z) | ((unsigned)f2bf(v1.w) << 16);
          af[rt] = p.v;
        } else {
          af[rt] = *(const bf16x8*)((const unsigned short*)A +
                                    (size_t)rowa[rt] * AK + koff + kt + quad * 8);
        }
      }
#pragma unroll
      for (int t = 0; t < NT; ++t) {
        bf16x8 bfr = *(const bf16x8*)&Bs[(t * 16 + m16) * KP + kt + quad * 8];
        acc[0][t] = __builtin_amdgcn_mfma_f32_16x16x32_bf16(af[0], bfr, acc[0][t], 0, 0, 0);
        acc[1][t] = __builtin_amdgcn_mfma_f32_16x16x32_bf16(af[1], bfr, acc[1][t], 0, 0, 0);
      }
    }
  }

  const float inv_std = rsqrtf(1.f + 1e-5f);
#pragma unroll
  for (int t = 0; t < NT; ++t) {
    int col = t * 16 + m16;
    float bv = bias[col];
    float sc = 1.f, bt2 = 0.f;
    if constexpr (EPI == EPI_BN) {
      sc = gamma[col] * inv_std;
      bt2 = beta[col];
    }
#pragma unroll
    for (int rt = 0; rt < 2; ++rt) {
#pragma unroll
      for (int r = 0; r < 4; ++r) {
        int row = row0 + wave * 32 + rt * 16 + quad * 4 + r;
        if (row < n) {
          float v = acc[rt][t][r] + bv;
          if constexpr (EPI == EPI_BN) v = fmaxf(v * sc + bt2, 0.f);
          else if constexpr (EPI == EPI_RELU) v = fmaxf(v, 0.f);
          if constexpr (OUTF32)
            ((float*)Cv)[(size_t)row * M + col] = v;
          else
            ((unsigned short*)Cv)[(size_t)row * M + col] = f2bf(v);
        }
      }
    }
  }
}

extern "C" void kernel_launch(void* const* d_in, const int* in_sizes, int n_in,
                              void* d_out, int out_size, void* d_ws, size_t ws_size,
                              hipStream_t stream) {
  const float* x     = (const float*)d_in[0];
  const int*   ei    = (const int*)d_in[1];
  const float* w_in  = (const float*)d_in[2];
  const float* b_in  = (const float*)d_in[3];
  const float* w_l1  = (const float*)d_in[4];
  const float* b_l1  = (const float*)d_in[5];
  const float* w_r1  = (const float*)d_in[6];
  const float* g1    = (const float*)d_in[7];
  const float* be1   = (const float*)d_in[8];
  const float* w_l2  = (const float*)d_in[9];
  const float* b_l2  = (const float*)d_in[10];
  const float* w_r2  = (const float*)d_in[11];
  const float* g2    = (const float*)d_in[12];
  const float* be2   = (const float*)d_in[13];
  const float* w_out = (const float*)d_in[14];
  const float* b_out = (const float*)d_in[15];
  float* out = (float*)d_out;

  int N = in_sizes[0] / DIN;
  int E = in_sizes[1] / 2;
  const int* src = ei;       // edge_index[0]
  const int* dst = ei + E;   // edge_index[1]

  char* ws = (char*)d_ws;
  size_t off = 0;
  auto alloc = [&](size_t bytes) -> char* {
    char* p = ws + off;
    off += (bytes + 255) & ~(size_t)255;
    return p;
  };
  unsigned short* buf0 = (unsigned short*)alloc((size_t)N * H * 2);  // h0 -> mean2
  unsigned short* buf1 = (unsigned short*)alloc((size_t)N * H * 2);  // mean1 -> h2
  unsigned short* buf2 = (unsigned short*)alloc((size_t)N * H * 2);  // h1
  int* deg     = (int*)alloc((size_t)(N + 1) * 4);  // deg[N] = alloc counter
  int* row_beg = (int*)alloc((size_t)N * 4);
  int* cursor  = (int*)alloc((size_t)N * 4);
  int* csr_src = (int*)alloc((size_t)E * 4);
  unsigned short* t_in  = (unsigned short*)alloc(32768 * 2);
  unsigned short* t_l1  = (unsigned short*)alloc(16384 * 2);
  unsigned short* t_r1  = (unsigned short*)alloc(16384 * 2);
  unsigned short* t_l2  = (unsigned short*)alloc(16384 * 2);
  unsigned short* t_r2  = (unsigned short*)alloc(16384 * 2);
  unsigned short* t_out = (unsigned short*)alloc(8192 * 2);
  int* counter = deg + N;
  (void)ws_size;

  // ---- CSR build + weight prep ----
  hipMemsetAsync(deg, 0, (size_t)(N + 1) * 4, stream);
  hist_kernel<<<(E + 255) / 256, 256, 0, stream>>>(dst, deg, E);
  alloc_kernel<<<(N + 255) / 256, 256, 0, stream>>>(deg, counter, row_beg, cursor, N);
  fill_kernel<<<(E + 255) / 256, 256, 0, stream>>>(src, dst, cursor, csr_src, E);
  prep_w<<<(106496 + 255) / 256, 256, 0, stream>>>(
      w_in, w_l1, w_r1, w_l2, w_r2, w_out, t_in, t_l1, t_r1, t_l2, t_r2, t_out);

  int gblocks = (N + 127) / 128;
  int ablocks = (N + 3) / 4;

  // h0 = relu(x @ w_in + b_in)          [fp32 A, K=256 via 2 phases]
  gemm_mfma<2, 128, 256, 128, EPI_RELU, true, false><<<gblocks, 256, 0, stream>>>(
      x, x, t_in, t_in, b_in, nullptr, nullptr, buf0, N);
  // mean1
  agg_kernel<<<ablocks, 256, 0, stream>>>((const unsigned*)buf0, row_beg, deg,
                                          csr_src, (unsigned*)buf1, N);
  // h1 = relu(bn(mean1@w_l1 + h0@w_r1 + b_l1))
  gemm_mfma<2, 0, 128, 128, EPI_BN, false, false><<<gblocks, 256, 0, stream>>>(
      buf1, buf0, t_l1, t_r1, b_l1, g1, be1, buf2, N);
  // mean2
  agg_kernel<<<ablocks, 256, 0, stream>>>((const unsigned*)buf2, row_beg, deg,
                                          csr_src, (unsigned*)buf0, N);
  // h2 = relu(bn(mean2@w_l2 + h1@w_r2 + b_l2))
  gemm_mfma<2, 0, 128, 128, EPI_BN, false, false><<<gblocks, 256, 0, stream>>>(
      buf0, buf2, t_l2, t_r2, b_l2, g2, be2, buf1, N);
  // out = h2 @ w_out + b_out
  gemm_mfma<1, 0, 128, 64, EPI_NONE, false, true><<<gblocks, 256, 0, stream>>>(
      buf1, buf1, t_out, t_out, b_out, nullptr, nullptr, out, N);
}